// Round 1
// baseline (1258.793 us; speedup 1.0000x reference)
//
#include <hip/hip_runtime.h>

#define DIM 64
#define NE 2048
#define NROWS 65536
#define HW 4096

static __device__ __forceinline__ float decayf() { return 0.99f; }

#define DECAYF 0.99f
#define OMDF ((float)(1.0 - 0.99))          // matches python (1.0 - DECAY) -> f32
#define EPSF 1e-5f
#define NEPSF ((float)(2048.0 * 1e-5))      // matches python n_embed*EPS -> f32

// ---------------- se[j] = sum_d E[d][j]^2 ----------------
__global__ __launch_bounds__(256) void se_kernel(const float* __restrict__ E,
                                                 float* __restrict__ se) {
  int j = blockIdx.x * 256 + threadIdx.x;
  float s = 0.f;
#pragma unroll
  for (int d = 0; d < DIM; ++d) {
    float v = E[d * NE + j];
    s += v * v;
  }
  se[j] = s;
}

// ---------------- argmin over codes ----------------
// block = 256 threads = 4 waves; wave q handles codes [q*512, q*512+512)
// lane r handles row blockIdx.x*64 + r. f row kept in VGPRs; E via scalar loads.
__global__ __launch_bounds__(256, 4) void argmin_kernel(const float* __restrict__ x,
                                                        const float* __restrict__ E,
                                                        const float* __restrict__ se,
                                                        int* __restrict__ ind,
                                                        float* __restrict__ ind_f) {
  const int tid = threadIdx.x;
  const int r = tid & 63;
  const int q = tid >> 6;
  const int row = blockIdx.x * 64 + r;
  const int b = row >> 12;
  const int hw = row & (HW - 1);
  const float* xr = x + b * (DIM * HW) + hw;

  float f[DIM];
  float sf = 0.f;
#pragma unroll
  for (int d = 0; d < DIM; ++d) {
    f[d] = xr[d * HW];
    sf += f[d] * f[d];
  }

  float mval = 3.4e38f;
  int midx = 0;
  const int j0 = q * (NE / 4);
  for (int j = j0; j < j0 + NE / 4; j += 8) {
    float a[8];
#pragma unroll
    for (int k = 0; k < 8; ++k) a[k] = 0.f;
#pragma unroll
    for (int d = 0; d < DIM; ++d) {
      const float fd = f[d];
      const float* ed = E + d * NE + j;   // wave-uniform address -> s_load
#pragma unroll
      for (int k = 0; k < 8; ++k) a[k] = fmaf(fd, ed[k], a[k]);
    }
#pragma unroll
    for (int k = 0; k < 8; ++k) {
      float dist = (sf - 2.f * a[k]) + se[j + k];  // same association as reference
      if (dist < mval) { mval = dist; midx = j + k; }
    }
  }

  __shared__ float svals[4][64];
  __shared__ int sidxs[4][64];
  svals[q][r] = mval;
  sidxs[q][r] = midx;
  __syncthreads();
  if (q == 0) {
#pragma unroll
    for (int k = 1; k < 4; ++k) {
      float v = svals[k][r];
      if (v < mval) { mval = v; midx = sidxs[k][r]; }  // strict < keeps lowest j on ties
    }
    ind[row] = midx;
    ind_f[row] = (float)midx;
  }
}

// ---------------- out (NCHW) + diff ----------------
__global__ __launch_bounds__(256) void out_diff_kernel(const float* __restrict__ x,
                                                       const float* __restrict__ E,
                                                       const int* __restrict__ ind,
                                                       float* __restrict__ out,
                                                       float* __restrict__ diff_acc) {
  const int t = threadIdx.x;
  float local = 0.f;
  const int base = blockIdx.x * 1024;
#pragma unroll
  for (int u = 0; u < 4; ++u) {
    int i = base + u * 256 + t;
    int hw = i & 4095;
    int bc = i >> 12;
    int c = bc & 63;
    int b = bc >> 6;
    int idx = ind[b * 4096 + hw];
    float qv = E[c * NE + idx];
    float xv = x[i];
    float dq = qv - xv;
    out[i] = xv + dq;       // replicate xp + (quantize - xp)
    local += dq * dq;
  }
#pragma unroll
  for (int off = 32; off > 0; off >>= 1) local += __shfl_down(local, off, 64);
  __shared__ float wsum[4];
  if ((t & 63) == 0) wsum[t >> 6] = local;
  __syncthreads();
  if (t == 0) {
    float s = wsum[0] + wsum[1] + wsum[2] + wsum[3];
    atomicAdd(diff_acc, s * (1.f / 4194304.f));   // 2^22 -> exact scale
  }
}

// ---------------- counts + embed_sum scatter ----------------
__global__ __launch_bounds__(256) void scatter_kernel(const float* __restrict__ x,
                                                      const int* __restrict__ ind,
                                                      float* __restrict__ counts,
                                                      float* __restrict__ esum) {
  const int row = blockIdx.x * 256 + threadIdx.x;
  const int idx = ind[row];
  atomicAdd(&counts[idx], 1.f);
  const int b = row >> 12;
  const int hw = row & 4095;
  const float* xr = x + b * (DIM * HW) + hw;
#pragma unroll
  for (int d = 0; d < DIM; ++d) {
    atomicAdd(&esum[d * NE + idx], xr[d * HW]);
  }
}

// ---------------- finalize: new_cluster_size (in place over counts) + n ----------------
__global__ __launch_bounds__(1024) void finalize_a(const float* __restrict__ cs_in,
                                                   float* __restrict__ ncs_slot,
                                                   float* __restrict__ n_out) {
  const int t = threadIdx.x;
  float local = 0.f;
#pragma unroll
  for (int u = 0; u < 2; ++u) {
    int k = u * 1024 + t;
    float v = DECAYF * cs_in[k] + OMDF * ncs_slot[k];
    ncs_slot[k] = v;
    local += v;
  }
#pragma unroll
  for (int off = 32; off > 0; off >>= 1) local += __shfl_down(local, off, 64);
  __shared__ float red[16];
  if ((t & 63) == 0) red[t >> 6] = local;
  __syncthreads();
  if (t == 0) {
    float s = 0.f;
#pragma unroll
    for (int k = 0; k < 16; ++k) s += red[k];
    *n_out = s;
  }
}

// ---------------- finalize: new_embed_avg (in place over esum) + new_embed ----------------
__global__ __launch_bounds__(256) void finalize_b(const float* __restrict__ ea_in,
                                                  float* __restrict__ nea_slot,
                                                  const float* __restrict__ ncs_slot,
                                                  const float* __restrict__ n_out,
                                                  float* __restrict__ ne_slot) {
  const int k = blockIdx.x * 256 + threadIdx.x;  // 131072
  const float n = *n_out;
  float nea = DECAYF * ea_in[k] + OMDF * nea_slot[k];
  nea_slot[k] = nea;
  float ncs = ncs_slot[k & (NE - 1)];
  float cs = (ncs + EPSF) / (n + NEPSF) * n;     // same association as reference
  ne_slot[k] = nea / cs;
}

extern "C" void kernel_launch(void* const* d_in, const int* in_sizes, int n_in,
                              void* d_out, int out_size, void* d_ws, size_t ws_size,
                              hipStream_t stream) {
  const float* x = (const float*)d_in[0];      // [16,64,64,64]
  const float* E = (const float*)d_in[1];      // [64,2048]
  const float* cs_in = (const float*)d_in[2];  // [2048]
  const float* ea_in = (const float*)d_in[3];  // [64,2048]
  float* out = (float*)d_out;

  // output offsets (floats)
  const size_t O_OUT = 0;
  const size_t O_DIFF = 4194304;
  const size_t O_IND = 4194305;
  const size_t O_NE = 4259841;    // new_embed [64,2048]
  const size_t O_NCS = 4390913;   // new_cluster_size [2048]
  const size_t O_NEA = 4392961;   // new_embed_avg [64,2048]

  // workspace layout
  float* se = (float*)d_ws;                                   // 2048 f
  int* ind = (int*)((char*)d_ws + 2048 * 4);                  // 65536 i
  float* n_out = (float*)((char*)d_ws + (2048 + 65536) * 4);  // 1 f

  // zero accumulation targets (capture-safe)
  hipMemsetAsync(out + O_DIFF, 0, 4, stream);
  hipMemsetAsync(out + O_NCS, 0, NE * 4, stream);
  hipMemsetAsync(out + O_NEA, 0, DIM * NE * 4, stream);

  se_kernel<<<NE / 256, 256, 0, stream>>>(E, se);
  argmin_kernel<<<NROWS / 64, 256, 0, stream>>>(x, E, se, ind, out + O_IND);
  out_diff_kernel<<<4096, 256, 0, stream>>>(x, E, ind, out + O_OUT, out + O_DIFF);
  scatter_kernel<<<NROWS / 256, 256, 0, stream>>>(x, ind, out + O_NCS, out + O_NEA);
  finalize_a<<<1, 1024, 0, stream>>>(cs_in, out + O_NCS, n_out);
  finalize_b<<<DIM * NE / 256, 256, 0, stream>>>(ea_in, out + O_NEA, out + O_NCS, n_out,
                                                 out + O_NE);
}

// Round 2
// 449.594 us; speedup vs baseline: 2.7998x; 2.7998x over previous
//
#include <hip/hip_runtime.h>

#define DIM 64
#define NE 2048
#define NROWS 65536
#define HW 4096

#define DECAYF 0.99f
#define OMDF ((float)(1.0 - 0.99))          // matches python (1.0 - DECAY) -> f32
#define EPSF 1e-5f
#define NEPSF ((float)(2048.0 * 1e-5))      // matches python n_embed*EPS -> f32

// ---------------- se[j] = sum_d E[d][j]^2 ----------------
__global__ __launch_bounds__(256) void se_kernel(const float* __restrict__ E,
                                                 float* __restrict__ se) {
  int j = blockIdx.x * 256 + threadIdx.x;
  float s = 0.f;
#pragma unroll
  for (int d = 0; d < DIM; ++d) {
    float v = E[d * NE + j];
    s += v * v;
  }
  se[j] = s;
}

// ---------------- argmin as LDS-tiled GEMM with fused argmin epilogue ----
// Block: 256 threads (4 waves), 128 rows x all 2048 codes, K = 64.
// Code tiles of 128; thread tile 8 rows x 8 codes (64 fp32 accumulators).
// rg = tid>>4 (16 row groups of 8), cg = tid&15 (16 code groups of 8).
// argmin over (se[j] - 2*dot) — sf is a per-row constant shift, monotone-safe.
#define BR 128
#define TC 128
__global__ __launch_bounds__(256, 2) void argmin_kernel(const float* __restrict__ x,
                                                        const float* __restrict__ E,
                                                        const float* __restrict__ se,
                                                        int* __restrict__ ind,
                                                        float* __restrict__ ind_f) {
  __shared__ float Xs[DIM][BR];   // [d][row]  32 KB
  __shared__ float Es[DIM][TC];   // [d][code] 32 KB
  const int tid = threadIdx.x;
  const int rg = tid >> 4;   // 0..15
  const int cg = tid & 15;   // 0..15
  const int B0 = blockIdx.x * BR;
  const int b = B0 >> 12;
  const int hw0 = B0 & 4095;
  const float* xb = x + (size_t)b * (DIM * HW) + hw0;

  // ---- stage Xs once: Xs[d][r] = x[b][d][hw0+r] (coalesced float4) ----
  float* Xf = &Xs[0][0];
#pragma unroll
  for (int k = 0; k < 8; ++k) {
    int i = k * 1024 + tid * 4;       // flat over [64][128]
    int d = i >> 7, r = i & 127;
    *(float4*)(Xf + i) = *(const float4*)(xb + d * HW + r);
  }

  float bv[8];
  int bi[8];
#pragma unroll
  for (int i2 = 0; i2 < 8; ++i2) { bv[i2] = 3.4e38f; bi[i2] = 0; }

  float* Ef = &Es[0][0];
  for (int t = 0; t < NE / TC; ++t) {
    __syncthreads();   // prev-tile reads done (and Xs writes ordered on t==0)
#pragma unroll
    for (int k = 0; k < 8; ++k) {
      int i = k * 1024 + tid * 4;     // flat over [64][128]
      int d = i >> 7, c = i & 127;
      *(float4*)(Ef + i) = *(const float4*)(E + d * NE + t * TC + c);
    }
    __syncthreads();

    float acc[8][8];
#pragma unroll
    for (int i2 = 0; i2 < 8; ++i2)
#pragma unroll
      for (int j = 0; j < 8; ++j) acc[i2][j] = 0.f;

#pragma unroll 8
    for (int d = 0; d < DIM; ++d) {   // serial d-chain: same rounding as round 1
      float4 xa = *(const float4*)&Xs[d][rg * 8];
      float4 xc = *(const float4*)&Xs[d][rg * 8 + 4];
      float4 ea = *(const float4*)&Es[d][cg * 8];
      float4 ec = *(const float4*)&Es[d][cg * 8 + 4];
      float xr[8] = {xa.x, xa.y, xa.z, xa.w, xc.x, xc.y, xc.z, xc.w};
      float er[8] = {ea.x, ea.y, ea.z, ea.w, ec.x, ec.y, ec.z, ec.w};
#pragma unroll
      for (int i2 = 0; i2 < 8; ++i2)
#pragma unroll
        for (int j = 0; j < 8; ++j) acc[i2][j] = fmaf(xr[i2], er[j], acc[i2][j]);
    }

    // per-tile argmin fold (codes ascending -> strict < keeps lowest index)
    float4 s0 = *(const float4*)(se + t * TC + cg * 8);
    float4 s1 = *(const float4*)(se + t * TC + cg * 8 + 4);
    float sv[8] = {s0.x, s0.y, s0.z, s0.w, s1.x, s1.y, s1.z, s1.w};
#pragma unroll
    for (int i2 = 0; i2 < 8; ++i2) {
#pragma unroll
      for (int j = 0; j < 8; ++j) {
        float dist = fmaf(-2.f, acc[i2][j], sv[j]);
        if (dist < bv[i2]) { bv[i2] = dist; bi[i2] = t * TC + cg * 8 + j; }
      }
    }
  }

  // cross-thread reduce over the 16 cg-lanes of each row group (within-wave)
#pragma unroll
  for (int i2 = 0; i2 < 8; ++i2) {
    float v = bv[i2];
    int ix = bi[i2];
#pragma unroll
    for (int off = 1; off < 16; off <<= 1) {
      float ov = __shfl_xor(v, off, 64);
      int oi = __shfl_xor(ix, off, 64);
      if (ov < v || (ov == v && oi < ix)) { v = ov; ix = oi; }
    }
    bv[i2] = v;
    bi[i2] = ix;
  }
  if (cg == 0) {
#pragma unroll
    for (int i2 = 0; i2 < 8; ++i2) {
      int grow = B0 + rg * 8 + i2;
      ind[grow] = bi[i2];
      ind_f[grow] = (float)bi[i2];
    }
  }
}

// ---------------- fused: out (NCHW) + diff + counts + embed_sum ----------
__global__ __launch_bounds__(256) void fuse_kernel(const float* __restrict__ x,
                                                   const float* __restrict__ E,
                                                   const int* __restrict__ ind,
                                                   float* __restrict__ out,
                                                   float* __restrict__ diff_acc,
                                                   float* __restrict__ counts,
                                                   float* __restrict__ esum) {
  const int t = threadIdx.x;
  float local = 0.f;
  const int base = blockIdx.x * 1024;
#pragma unroll
  for (int u = 0; u < 4; ++u) {
    int i = base + u * 256 + t;
    int hw = i & 4095;
    int bc = i >> 12;
    int c = bc & 63;
    int b = bc >> 6;
    int idx = ind[b * 4096 + hw];
    float xv = x[i];
    float qv = E[c * NE + idx];
    float dq = qv - xv;
    out[i] = xv + dq;                      // replicate xp + (quantize - xp)
    local += dq * dq;
    atomicAdd(&esum[c * NE + idx], xv);    // embed_sum scatter (1 atomic/elem)
    if (c == 0) atomicAdd(&counts[idx], 1.f);
  }
#pragma unroll
  for (int off = 32; off > 0; off >>= 1) local += __shfl_down(local, off, 64);
  __shared__ float wsum[4];
  if ((t & 63) == 0) wsum[t >> 6] = local;
  __syncthreads();
  if (t == 0) {
    float s = wsum[0] + wsum[1] + wsum[2] + wsum[3];
    atomicAdd(diff_acc, s * (1.f / 4194304.f));
  }
}

// ---------------- finalize: new_cluster_size (in place) + n ----------------
__global__ __launch_bounds__(1024) void finalize_a(const float* __restrict__ cs_in,
                                                   float* __restrict__ ncs_slot,
                                                   float* __restrict__ n_out) {
  const int t = threadIdx.x;
  float local = 0.f;
#pragma unroll
  for (int u = 0; u < 2; ++u) {
    int k = u * 1024 + t;
    float v = DECAYF * cs_in[k] + OMDF * ncs_slot[k];
    ncs_slot[k] = v;
    local += v;
  }
#pragma unroll
  for (int off = 32; off > 0; off >>= 1) local += __shfl_down(local, off, 64);
  __shared__ float red[16];
  if ((t & 63) == 0) red[t >> 6] = local;
  __syncthreads();
  if (t == 0) {
    float s = 0.f;
#pragma unroll
    for (int k = 0; k < 16; ++k) s += red[k];
    *n_out = s;
  }
}

// ---------------- finalize: new_embed_avg (in place) + new_embed ----------
__global__ __launch_bounds__(256) void finalize_b(const float* __restrict__ ea_in,
                                                  float* __restrict__ nea_slot,
                                                  const float* __restrict__ ncs_slot,
                                                  const float* __restrict__ n_out,
                                                  float* __restrict__ ne_slot) {
  const int k = blockIdx.x * 256 + threadIdx.x;  // 131072
  const float n = *n_out;
  float nea = DECAYF * ea_in[k] + OMDF * nea_slot[k];
  nea_slot[k] = nea;
  float ncs = ncs_slot[k & (NE - 1)];
  float cs = (ncs + EPSF) / (n + NEPSF) * n;
  ne_slot[k] = nea / cs;
}

extern "C" void kernel_launch(void* const* d_in, const int* in_sizes, int n_in,
                              void* d_out, int out_size, void* d_ws, size_t ws_size,
                              hipStream_t stream) {
  const float* x = (const float*)d_in[0];      // [16,64,64,64]
  const float* E = (const float*)d_in[1];      // [64,2048]
  const float* cs_in = (const float*)d_in[2];  // [2048]
  const float* ea_in = (const float*)d_in[3];  // [64,2048]
  float* out = (float*)d_out;

  // output offsets (floats)
  const size_t O_OUT = 0;
  const size_t O_DIFF = 4194304;
  const size_t O_IND = 4194305;
  const size_t O_NE = 4259841;    // new_embed [64,2048]
  const size_t O_NCS = 4390913;   // new_cluster_size [2048]
  const size_t O_NEA = 4392961;   // new_embed_avg [64,2048]

  // workspace layout
  float* se = (float*)d_ws;                                   // 2048 f
  int* ind = (int*)((char*)d_ws + 2048 * 4);                  // 65536 i
  float* n_out = (float*)((char*)d_ws + (2048 + 65536) * 4);  // 1 f

  // zero accumulation targets (capture-safe)
  hipMemsetAsync(out + O_DIFF, 0, 4, stream);
  hipMemsetAsync(out + O_NCS, 0, NE * 4, stream);
  hipMemsetAsync(out + O_NEA, 0, DIM * NE * 4, stream);

  se_kernel<<<NE / 256, 256, 0, stream>>>(E, se);
  argmin_kernel<<<NROWS / BR, 256, 0, stream>>>(x, E, se, ind, out + O_IND);
  fuse_kernel<<<4096, 256, 0, stream>>>(x, E, ind, out + O_OUT, out + O_DIFF,
                                        out + O_NCS, out + O_NEA);
  finalize_a<<<1, 1024, 0, stream>>>(cs_in, out + O_NCS, n_out);
  finalize_b<<<DIM * NE / 256, 256, 0, stream>>>(ea_in, out + O_NEA, out + O_NCS, n_out,
                                                 out + O_NE);
}